// Round 6
// baseline (755.029 us; speedup 1.0000x reference)
//
#include <hip/hip_runtime.h>

#define T_STEPS 365
#define BATCH   2048
#define INP     9
#define HID     50
#define MB      4           // valid batch per block (MFMA col dim is still 16)
#define MROW    16          // MFMA B-operand rows in LDS (12 are padding)
#define NBLK    (BATCH/MB)  // 512 blocks -> 2 blocks/CU, independent barrier groups
#define NT      512         // 8 waves: 0-3 layer1, 4-7 layer0
#define NTILES  13          // 208 gate rows >= 200
#define TPW     4

typedef __attribute__((ext_vector_type(8))) short short8;
typedef __attribute__((ext_vector_type(4))) float float4v;

__device__ __forceinline__ unsigned short f2bf(float v) {
    unsigned u = __builtin_bit_cast(unsigned, v);
    unsigned r = (u + 0x7FFFu + ((u >> 16) & 1u)) >> 16;
    return (unsigned short)r;
}
__device__ __forceinline__ float sig_(float x) {
    return __builtin_amdgcn_rcpf(1.f + __expf(-x));
}
__device__ __forceinline__ float tanh_(float x) {
    return 1.f - 2.f * __builtin_amdgcn_rcpf(__expf(2.f * x) + 1.f);
}

// HX[p]: [16 rows][128 bf16 cols]: 0-49 h0 | 50-58 x | 59-63 zero | 64-113 h1 | 114-127 zero
// Rows 0-3 are real batch; rows 4-15 are bounded garbage (never stored out).
__device__ __forceinline__ int hx_off(int m, int k) {   // ushort units
    return (m * 128 + k) ^ ((m & 7) << 3);
}

// Layer-pipelined LSTM: phase t runs layer0(t) on waves 4-7 concurrently with
// layer1(t-1) on waves 0-3; ONE barrier per phase. 512 blocks / 256 CUs -> two
// INDEPENDENT barrier groups per CU fill each other's dependency stalls.
__global__ __launch_bounds__(NT, 4)
void lstm_pipe2g(const float* __restrict__ x,
                 const float* __restrict__ w_ih0, const float* __restrict__ w_hh0,
                 const float* __restrict__ b_ih0, const float* __restrict__ b_hh0,
                 const float* __restrict__ w_ih1, const float* __restrict__ w_hh1,
                 const float* __restrict__ b_ih1, const float* __restrict__ b_hh1,
                 const float* __restrict__ fc_w, const float* __restrict__ fc_b,
                 float* __restrict__ out)
{
    __shared__ __align__(16) unsigned short HX[2][MROW * 128];
    __shared__ float FCP[2][4][MB];   // double-buffered FC partials per L1 wave

    const int t    = threadIdx.x;
    const int w    = t >> 6;
    const int lid  = t & 63;
    const int mcol = lid & 15;
    const int kgrp = lid >> 4;
    const int kb8  = kgrp * 8;
    const int b0   = blockIdx.x * MB;
    const bool isL1 = (w < 4);
    const int v    = w & 3;                  // role-wave index 0..3
    const float fcb = fc_b[0];

    // ---- weights: wave v owns tiles {v, v+4, v+8, v+12} (valid if < 13) ----
    // gate-interleaved rows: tile row r = 4*unit + gate  ->  original row = gate*50 + unit
    short8 wA[TPW][4];
    float  bs[TPW][4], fcw[TPW], cst[TPW];
    const float* bih = isL1 ? b_ih1 : b_ih0;
    const float* bhh = isL1 ? b_hh1 : b_hh0;

    #pragma unroll
    for (int tt = 0; tt < TPW; ++tt) {
        const int T  = v + 4 * tt;
        const bool tv = (T < NTILES);
        const int r  = T * 16 + mcol;
        const bool rv = tv && (r < 4 * HID);
        const int u_r = r >> 2, g_r = r & 3;
        const int orig = g_r * HID + u_r;
        if (isL1) {
            // layer1 K=128: [w_ih1 on h0(50) | 0 | w_hh1 on h1(50) | 0]
            #pragma unroll
            for (int kt = 0; kt < 4; ++kt) {
                short8 f;
                #pragma unroll
                for (int j = 0; j < 8; ++j) {
                    int k = kt * 32 + kb8 + j;
                    float val = 0.f;
                    if (rv) {
                        if (k < HID)                      val = w_ih1[orig * HID + k];
                        else if (k >= 64 && k < 64 + HID) val = w_hh1[orig * HID + (k - 64)];
                    }
                    f[j] = (short)f2bf(val);
                }
                wA[tt][kt] = f;
            }
        } else {
            // layer0 K=64: [w_hh0 on h0(50) | w_ih0 on x(9) | 0]
            #pragma unroll
            for (int kt = 0; kt < 2; ++kt) {
                short8 f;
                #pragma unroll
                for (int j = 0; j < 8; ++j) {
                    int k = kt * 32 + kb8 + j;
                    float val = 0.f;
                    if (rv) {
                        if (k < HID)            val = w_hh0[orig * HID + k];
                        else if (k < HID + INP) val = w_ih0[orig * INP + (k - HID)];
                    }
                    f[j] = (short)f2bf(val);
                }
                wA[tt][kt] = f;
            }
            wA[tt][2] = short8{}; wA[tt][3] = short8{};
        }
        const int u_lane = T * 4 + kgrp;
        #pragma unroll
        for (int rr = 0; rr < 4; ++rr) {
            int row = T * 16 + kgrp * 4 + rr;   // = 4*u_lane + rr
            bool bvv = tv && (row < 4 * HID);
            int uu = row >> 2;
            bs[tt][rr] = bvv ? (bih[rr * HID + uu] + bhh[rr * HID + uu]) : 0.f;
        }
        fcw[tt] = (isL1 && tv && u_lane < HID) ? fc_w[u_lane] : 0.f;
        cst[tt] = 0.f;
    }

    // ---- x-loader identity (wave 4): MB*INP = 36 values ----
    const bool xact = (w == 4 && lid < MB * INP);
    const int xm = xact ? lid / INP : 0, xj = xact ? lid % INP : 0;

    // ---- init LDS ----
    for (int i = t; i < 2 * MROW * 128; i += NT) (&HX[0][0])[i] = 0;
    if (t < 2 * 4 * MB) (&FCP[0][0][0])[t] = 0.f;
    __syncthreads();
    float xreg = 0.f;
    if (xact) {
        // x(0) into buf[1] (phase 0 reads cur = 1); xreg <- x(1)
        HX[1][hx_off(xm, HID + xj)] = f2bf(x[(size_t)(b0 + xm) * INP + xj]);
        xreg = x[((size_t)BATCH + b0 + xm) * INP + xj];
    }
    __syncthreads();

    for (int ph = 0; ph < T_STEPS + 2; ++ph) {
        const int cur = (ph + 1) & 1, nxt = ph & 1;

        short8 f0 = *(const short8*)&HX[cur][hx_off(mcol, kb8)];
        short8 f1 = *(const short8*)&HX[cur][hx_off(mcol, 32 + kb8)];

        if (isL1) {
            // ---- layer1: h1(ph-1) from h0(ph-1), h1(ph-2); FC partials ----
            if (ph >= 1 && ph <= T_STEPS) {
                short8 f2 = *(const short8*)&HX[cur][hx_off(mcol, 64 + kb8)];
                short8 f3 = *(const short8*)&HX[cur][hx_off(mcol, 96 + kb8)];
                float h1v[TPW];
                float fcp = 0.f;
                #pragma unroll
                for (int tt = 0; tt < TPW; ++tt) {
                    const int T = v + 4 * tt;
                    if (T < NTILES) {
                        // two independent 2-chains, summed at the end
                        float4v accA = {bs[tt][0], bs[tt][1], bs[tt][2], bs[tt][3]};
                        float4v accB = {0.f, 0.f, 0.f, 0.f};
                        accA = __builtin_amdgcn_mfma_f32_16x16x32_bf16(wA[tt][0], f0, accA, 0, 0, 0);
                        accB = __builtin_amdgcn_mfma_f32_16x16x32_bf16(wA[tt][2], f2, accB, 0, 0, 0);
                        accA = __builtin_amdgcn_mfma_f32_16x16x32_bf16(wA[tt][1], f1, accA, 0, 0, 0);
                        accB = __builtin_amdgcn_mfma_f32_16x16x32_bf16(wA[tt][3], f3, accB, 0, 0, 0);
                        float a0 = accA[0] + accB[0], a1 = accA[1] + accB[1];
                        float a2 = accA[2] + accB[2], a3 = accA[3] + accB[3];
                        float gi = sig_(a0), gf = sig_(a1);
                        float gg = tanh_(a2), go = sig_(a3);
                        cst[tt] = gf * cst[tt] + gi * gg;
                        h1v[tt] = go * tanh_(cst[tt]);
                        fcp += fcw[tt] * h1v[tt];
                    }
                }
                #pragma unroll
                for (int tt = 0; tt < TPW; ++tt) {
                    const int T = v + 4 * tt, u = T * 4 + kgrp;
                    if (T < NTILES && u < HID)
                        HX[nxt][hx_off(mcol, 64 + u)] = f2bf(h1v[tt]);
                }
                fcp += __shfl_xor(fcp, 16);
                fcp += __shfl_xor(fcp, 32);
                if (lid < MB) FCP[ph & 1][v][lid] = fcp;
            }
        } else {
            // ---- layer0: h0(ph) from h0(ph-1), x(ph) ----
            if (ph < T_STEPS) {
                float h0v[TPW];
                #pragma unroll
                for (int tt = 0; tt < TPW; ++tt) {
                    const int T = v + 4 * tt;
                    if (T < NTILES) {
                        float4v acc = {bs[tt][0], bs[tt][1], bs[tt][2], bs[tt][3]};
                        acc = __builtin_amdgcn_mfma_f32_16x16x32_bf16(wA[tt][0], f0, acc, 0, 0, 0);
                        acc = __builtin_amdgcn_mfma_f32_16x16x32_bf16(wA[tt][1], f1, acc, 0, 0, 0);
                        float gi = sig_(acc[0]), gf = sig_(acc[1]);
                        float gg = tanh_(acc[2]), go = sig_(acc[3]);
                        cst[tt] = gf * cst[tt] + gi * gg;
                        h0v[tt] = go * tanh_(cst[tt]);
                    }
                }
                #pragma unroll
                for (int tt = 0; tt < TPW; ++tt) {
                    const int T = v + 4 * tt, u = T * 4 + kgrp;
                    if (T < NTILES && u < HID)
                        HX[nxt][hx_off(mcol, u)] = f2bf(h0v[tt]);
                }
            }
            // ---- x staging: write x(ph+1) to nxt, prefetch x(ph+2) ----
            if (xact) {
                if (ph + 1 < T_STEPS) HX[nxt][hx_off(xm, HID + xj)] = f2bf(xreg);
                if (ph + 2 < T_STEPS) xreg = x[((size_t)(ph + 2) * BATCH + b0 + xm) * INP + xj];
            }
            // ---- out writer (wave 7): out[ph-2] from FCP written at ph-1 ----
            if (w == 7 && lid < MB && ph >= 2) {
                const int rp = (ph - 1) & 1;
                float s = fcb + FCP[rp][0][lid] + FCP[rp][1][lid]
                              + FCP[rp][2][lid] + FCP[rp][3][lid];
                out[(size_t)(ph - 2) * BATCH + b0 + lid] = s;
            }
        }
        __syncthreads();
    }
}

extern "C" void kernel_launch(void* const* d_in, const int* in_sizes, int n_in,
                              void* d_out, int out_size, void* d_ws, size_t ws_size,
                              hipStream_t stream) {
    const float* x     = (const float*)d_in[0];
    const float* w_ih0 = (const float*)d_in[1];
    const float* w_hh0 = (const float*)d_in[2];
    const float* b_ih0 = (const float*)d_in[3];
    const float* b_hh0 = (const float*)d_in[4];
    const float* w_ih1 = (const float*)d_in[5];
    const float* w_hh1 = (const float*)d_in[6];
    const float* b_ih1 = (const float*)d_in[7];
    const float* b_hh1 = (const float*)d_in[8];
    const float* fc_w  = (const float*)d_in[9];
    const float* fc_b  = (const float*)d_in[10];
    float* out = (float*)d_out;

    lstm_pipe2g<<<dim3(NBLK), dim3(NT), 0, stream>>>(
        x, w_ih0, w_hh0, b_ih0, b_hh0,
        w_ih1, w_hh1, b_ih1, b_hh1, fc_w, fc_b, out);
}

// Round 7
// 349.247 us; speedup vs baseline: 2.1619x; 2.1619x over previous
//
#include <hip/hip_runtime.h>

#define T_STEPS 365
#define BATCH   2048
#define INP     9
#define HID     50
#define MB      16          // batch per block (MFMA col dim)
#define NBLK    (BATCH/MB)  // 128
#define NT      1024        // 16 waves: 0-7 layer1, 8-15 layer0
#define NTILES  13          // 208 gate rows >= 200
#define TPW     2

#define L2E     1.4426950408889634f

typedef __attribute__((ext_vector_type(8))) short short8;
typedef __attribute__((ext_vector_type(4))) float float4v;

__device__ __forceinline__ unsigned short f2bf(float v) {
    unsigned u = __builtin_bit_cast(unsigned, v);
    unsigned r = (u + 0x7FFFu + ((u >> 16) & 1u)) >> 16;
    return (unsigned short)r;
}

// lgkmcnt-only phase barrier: LDS writes drain, global loads stay in flight
// (compiler inserts counted vmcnt waits at their uses, a full phase later).
#define PHASE_BARRIER() do {                                  \
    asm volatile("s_waitcnt lgkmcnt(0)" ::: "memory");        \
    __builtin_amdgcn_s_barrier();                             \
    __builtin_amdgcn_sched_barrier(0);                        \
} while (0)

// HX[p]: [16 batch rows][128 bf16 cols]: 0-49 h0 | 50-58 x | 59-63 zero | 64-113 h1 | 114-127 zero
// XOR swizzle keeps b128 fragment reads low-conflict.
__device__ __forceinline__ int hx_off(int m, int k) {   // ushort units
    return (m * 128 + k) ^ ((m & 7) << 3);
}

// Layer-pipelined LSTM, 16 waves: phase t runs layer0(t) on waves 8-15
// concurrently with layer1(t-1) on waves 0-7; ONE lgkm-only barrier per phase.
// Gate weights/biases pre-scaled by -log2e (i,f,o) / -2log2e (g) so the cell
// update is pure {exp2, rcp, fma} with no muls/clamps on the critical chain.
__global__ __launch_bounds__(NT, 4)
void lstm_pipe16b(const float* __restrict__ x,
                  const float* __restrict__ w_ih0, const float* __restrict__ w_hh0,
                  const float* __restrict__ b_ih0, const float* __restrict__ b_hh0,
                  const float* __restrict__ w_ih1, const float* __restrict__ w_hh1,
                  const float* __restrict__ b_ih1, const float* __restrict__ b_hh1,
                  const float* __restrict__ fc_w, const float* __restrict__ fc_b,
                  float* __restrict__ out)
{
    __shared__ __align__(16) unsigned short HX[2][MB * 128];
    __shared__ float FCP[2][8][MB];   // double-buffered FC partials per L1 wave

    const int t    = threadIdx.x;
    const int w    = t >> 6;
    const int lid  = t & 63;
    const int mcol = lid & 15;
    const int kgrp = lid >> 4;
    const int kb8  = kgrp * 8;
    const int b0   = blockIdx.x * MB;
    const bool isL1 = (w < 8);
    const int v    = w & 7;                  // role-wave index 0..7
    const float fcb = fc_b[0];

    // ---- weights: wave v owns tiles {v, v+8} (valid if < 13) ----
    // gate-interleaved rows: tile row r = 4*unit + gate  ->  original row = gate*50 + unit
    short8 wA[TPW][4];
    float  bs[TPW][4], fcw[TPW], cst[TPW];
    const float* bih = isL1 ? b_ih1 : b_ih0;
    const float* bhh = isL1 ? b_hh1 : b_hh0;

    #pragma unroll
    for (int tt = 0; tt < TPW; ++tt) {
        const int T  = v + 8 * tt;
        const bool tv = (T < NTILES);
        const int r  = T * 16 + mcol;
        const bool rv = tv && (r < 4 * HID);
        const int u_r = r >> 2, g_r = r & 3;
        const int orig = g_r * HID + u_r;
        const float rsc = (g_r == 2) ? (-2.f * L2E) : (-L2E);   // exp2 prescale
        #pragma unroll
        for (int kt = 0; kt < 4; ++kt) {
            short8 f;
            #pragma unroll
            for (int j = 0; j < 8; ++j) {
                int k = kt * 32 + kb8 + j;
                float val = 0.f;
                if (rv) {
                    if (isL1) {
                        if (k < HID)                      val = w_ih1[orig * HID + k];
                        else if (k >= 64 && k < 64 + HID) val = w_hh1[orig * HID + (k - 64)];
                    } else {
                        if (k < HID)            val = w_hh0[orig * HID + k];
                        else if (k < HID + INP) val = w_ih0[orig * INP + (k - HID)];
                    }
                }
                f[j] = (short)f2bf(val * rsc);
            }
            wA[tt][kt] = f;
        }
        const int u_lane = T * 4 + kgrp;
        #pragma unroll
        for (int rr = 0; rr < 4; ++rr) {
            int row = T * 16 + kgrp * 4 + rr;   // = 4*u_lane + rr
            bool bvv = tv && (row < 4 * HID);
            int uu = row >> 2;
            const float bsc = (rr == 2) ? (-2.f * L2E) : (-L2E);
            bs[tt][rr] = bvv ? (bih[rr * HID + uu] + bhh[rr * HID + uu]) * bsc : 0.f;
        }
        fcw[tt] = (isL1 && tv && u_lane < HID) ? fc_w[u_lane] : 0.f;
        cst[tt] = 0.f;
    }

    // ---- x-loader identity (L0 waves 8,9,10): 144 values ----
    int xi = -1;
    if (w == 8) xi = lid;
    else if (w == 9) xi = 64 + lid;
    else if (w == 10 && lid < 16) xi = 128 + lid;
    const bool xact = (xi >= 0 && xi < MB * INP);
    const int xm = xact ? xi / INP : 0, xj = xact ? xi % INP : 0;

    // ---- init LDS ----
    for (int i = t; i < 2 * MB * 128; i += NT) (&HX[0][0])[i] = 0;
    if (t < 2 * 8 * MB) (&FCP[0][0][0])[t] = 0.f;
    __syncthreads();
    float xreg = 0.f;
    if (xact) {
        // x(0) into buf[1] (phase 0 reads cur = 1); xreg <- x(1)
        HX[1][hx_off(xm, HID + xj)] = f2bf(x[(size_t)(b0 + xm) * INP + xj]);
        xreg = x[((size_t)BATCH + b0 + xm) * INP + xj];
    }
    __syncthreads();

    for (int ph = 0; ph < T_STEPS + 2; ++ph) {
        const int cur = (ph + 1) & 1, nxt = ph & 1;

        // issue x(ph+2) load at phase TOP: a full phase to land before its
        // LDS-staging use at ph+1; raw barrier below does NOT drain it.
        float xnew = 0.f;
        if (xact && ph + 2 < T_STEPS)
            xnew = x[((size_t)(ph + 2) * BATCH + b0 + xm) * INP + xj];

        short8 f0 = *(const short8*)&HX[cur][hx_off(mcol, kb8)];
        short8 f1 = *(const short8*)&HX[cur][hx_off(mcol, 32 + kb8)];

        if (isL1) {
            // ---- layer1: h1(ph-1) from h0(ph-1), h1(ph-2); FC partials ----
            if (ph >= 1 && ph <= T_STEPS) {
                short8 f2 = *(const short8*)&HX[cur][hx_off(mcol, 64 + kb8)];
                short8 f3 = *(const short8*)&HX[cur][hx_off(mcol, 96 + kb8)];
                float h1v[TPW];
                float fcp = 0.f;
                #pragma unroll
                for (int tt = 0; tt < TPW; ++tt) {
                    const int T = v + 8 * tt;
                    if (T < NTILES) {
                        // two independent 2-chains, summed at the end
                        float4v accA = {bs[tt][0], bs[tt][1], bs[tt][2], bs[tt][3]};
                        float4v accB = {0.f, 0.f, 0.f, 0.f};
                        accA = __builtin_amdgcn_mfma_f32_16x16x32_bf16(wA[tt][0], f0, accA, 0, 0, 0);
                        accB = __builtin_amdgcn_mfma_f32_16x16x32_bf16(wA[tt][2], f2, accB, 0, 0, 0);
                        accA = __builtin_amdgcn_mfma_f32_16x16x32_bf16(wA[tt][1], f1, accA, 0, 0, 0);
                        accB = __builtin_amdgcn_mfma_f32_16x16x32_bf16(wA[tt][3], f3, accB, 0, 0, 0);
                        float Ei = __builtin_amdgcn_exp2f(accA[0] + accB[0]);
                        float Ef = __builtin_amdgcn_exp2f(accA[1] + accB[1]);
                        float Eg = __builtin_amdgcn_exp2f(accA[2] + accB[2]);
                        float Eo = __builtin_amdgcn_exp2f(accA[3] + accB[3]);
                        float gi = __builtin_amdgcn_rcpf(1.f + Ei);
                        float gf = __builtin_amdgcn_rcpf(1.f + Ef);
                        float g2 = __builtin_amdgcn_rcpf(1.f + Eg);
                        float go = __builtin_amdgcn_rcpf(1.f + Eo);
                        float gg = __builtin_fmaf(2.f, g2, -1.f);
                        cst[tt] = gf * cst[tt] + gi * gg;
                        float Ec = __builtin_amdgcn_exp2f(cst[tt] * (-2.f * L2E));
                        float tc = __builtin_fmaf(2.f, __builtin_amdgcn_rcpf(1.f + Ec), -1.f);
                        h1v[tt] = go * tc;
                        fcp += fcw[tt] * h1v[tt];
                    }
                }
                #pragma unroll
                for (int tt = 0; tt < TPW; ++tt) {
                    const int T = v + 8 * tt, u = T * 4 + kgrp;
                    if (T < NTILES && u < HID)
                        HX[nxt][hx_off(mcol, 64 + u)] = f2bf(h1v[tt]);
                }
                fcp += __shfl_xor(fcp, 16);
                fcp += __shfl_xor(fcp, 32);
                if (lid < MB) FCP[ph & 1][v][lid] = fcp;
            }
        } else {
            // ---- layer0: h0(ph) from h0(ph-1), x(ph) ----
            if (ph < T_STEPS) {
                float h0v[TPW];
                #pragma unroll
                for (int tt = 0; tt < TPW; ++tt) {
                    const int T = v + 8 * tt;
                    if (T < NTILES) {
                        float4v acc = {bs[tt][0], bs[tt][1], bs[tt][2], bs[tt][3]};
                        acc = __builtin_amdgcn_mfma_f32_16x16x32_bf16(wA[tt][0], f0, acc, 0, 0, 0);
                        acc = __builtin_amdgcn_mfma_f32_16x16x32_bf16(wA[tt][1], f1, acc, 0, 0, 0);
                        float Ei = __builtin_amdgcn_exp2f(acc[0]);
                        float Ef = __builtin_amdgcn_exp2f(acc[1]);
                        float Eg = __builtin_amdgcn_exp2f(acc[2]);
                        float Eo = __builtin_amdgcn_exp2f(acc[3]);
                        float gi = __builtin_amdgcn_rcpf(1.f + Ei);
                        float gf = __builtin_amdgcn_rcpf(1.f + Ef);
                        float g2 = __builtin_amdgcn_rcpf(1.f + Eg);
                        float go = __builtin_amdgcn_rcpf(1.f + Eo);
                        float gg = __builtin_fmaf(2.f, g2, -1.f);
                        cst[tt] = gf * cst[tt] + gi * gg;
                        float Ec = __builtin_amdgcn_exp2f(cst[tt] * (-2.f * L2E));
                        float tc = __builtin_fmaf(2.f, __builtin_amdgcn_rcpf(1.f + Ec), -1.f);
                        h0v[tt] = go * tc;
                    }
                }
                #pragma unroll
                for (int tt = 0; tt < TPW; ++tt) {
                    const int T = v + 8 * tt, u = T * 4 + kgrp;
                    if (T < NTILES && u < HID)
                        HX[nxt][hx_off(mcol, u)] = f2bf(h0v[tt]);
                }
            }
            // ---- x staging: write x(ph+1) (loaded at ph-1 top, long landed) ----
            if (xact && ph + 1 < T_STEPS)
                HX[nxt][hx_off(xm, HID + xj)] = f2bf(xreg);
            // ---- out writer (wave 15): out[ph-2] from FCP written at ph-1 ----
            if (w == 15 && lid < MB && ph >= 2) {
                const int rp = (ph - 1) & 1;
                float s = fcb;
                #pragma unroll
                for (int ww = 0; ww < 8; ++ww) s += FCP[rp][ww][lid];
                out[(size_t)(ph - 2) * BATCH + b0 + lid] = s;
            }
        }
        xreg = xnew;
        PHASE_BARRIER();
    }
}

extern "C" void kernel_launch(void* const* d_in, const int* in_sizes, int n_in,
                              void* d_out, int out_size, void* d_ws, size_t ws_size,
                              hipStream_t stream) {
    const float* x     = (const float*)d_in[0];
    const float* w_ih0 = (const float*)d_in[1];
    const float* w_hh0 = (const float*)d_in[2];
    const float* b_ih0 = (const float*)d_in[3];
    const float* b_hh0 = (const float*)d_in[4];
    const float* w_ih1 = (const float*)d_in[5];
    const float* w_hh1 = (const float*)d_in[6];
    const float* b_ih1 = (const float*)d_in[7];
    const float* b_hh1 = (const float*)d_in[8];
    const float* fc_w  = (const float*)d_in[9];
    const float* fc_b  = (const float*)d_in[10];
    float* out = (float*)d_out;

    lstm_pipe16b<<<dim3(NBLK), dim3(NT), 0, stream>>>(
        x, w_ih0, w_hh0, b_ih0, b_hh0,
        w_ih1, w_hh1, b_ih1, b_hh1, fc_w, fc_b, out);
}